// Round 25
// baseline (170.037 us; speedup 1.0000x reference)
//
#include <hip/hip_runtime.h>
#include <hip/hip_bf16.h>

typedef short v8s __attribute__((ext_vector_type(8)));
typedef float v4f __attribute__((ext_vector_type(4)));

#define THREADS 512      // 8 waves; each wave: 8 tiles x 16 rows = 128 rows
#define WAVES   8
#define NTILES  8
#define BMROWS  1024     // rows per block -> grid = 256 = exactly 1 block/CU
// d_ws frag order: W1 0-48, W2 49-76, W3 77-92 (slot s at LDS s*1024)
#define W1F     0
#define W2F     49
#define W3F     77
#define SLABB   95232                    // 93 frag slots end here
#define SLAB_STRIDE 264
#define SLAB_SIZE   4224                 // 16 rows * 264
#define LDS_TOTAL   (SLABB + WAVES * SLAB_SIZE)   // 129,024 B -> 1 block/CU

__device__ __forceinline__ unsigned short f2bf(float f) {
    union { __hip_bfloat16 h; unsigned short u; } c;
    c.h = __float2bfloat16(f);
    return c.u;
}
__device__ __forceinline__ unsigned pk2(float a, float b) {
    return (unsigned)f2bf(a) | ((unsigned)f2bf(b) << 16);
}
__device__ __forceinline__ v4f mfma16(v8s a, v8s b, v4f c) {
    return __builtin_amdgcn_mfma_f32_16x16x32_bf16(a, b, c, 0, 0, 0);
}
__device__ __forceinline__ v8s mkfrag(float4 a, float4 b) {
    union { unsigned u[4]; v8s s; } t;
    t.u[0] = pk2(a.x, a.y); t.u[1] = pk2(a.z, a.w);
    t.u[2] = pk2(b.x, b.y); t.u[3] = pk2(b.z, b.w);
    return t.s;
}
__device__ __forceinline__ void gload_lds16(const void* g, void* l) {
    __builtin_amdgcn_global_load_lds(
        (const __attribute__((address_space(1))) void*)g,
        (__attribute__((address_space(3))) void*)l, 16, 0, 0);
}

// ---- prep: weights -> MFMA B-fragment layout (bf16, zero-padded) ----------
// frag(nt,kc): lane l holds B[k = kc*32+(l>>4)*8+j][n = nt*16+(l&15)], j=0..7
__global__ void prep_weights(const float* __restrict__ W1,
                             const float* __restrict__ W2,
                             const float* __restrict__ W3,
                             uint4* __restrict__ wf) {
    const int bid = blockIdx.x, l = threadIdx.x;
    const float* W; int K, N, KC, base, f;
    if (bid < 49)      { W = W1; K = 200; N = 100; KC = 7; base = W1F * 64; f = bid; }
    else if (bid < 77) { W = W2; K = 100; N = 100; KC = 4; base = W2F * 64; f = bid - 49; }
    else               { W = W3; K = 100; N = 64;  KC = 4; base = W3F * 64; f = bid - 77; }
    const int kc = f % KC;
    const int n  = (f / KC) * 16 + (l & 15);
    unsigned u[4];
    #pragma unroll
    for (int p = 0; p < 4; ++p) {
        const int k0 = kc * 32 + (l >> 4) * 8 + p * 2;
        const float a = (k0     < K && n < N) ? W[(size_t)k0 * N + n]       : 0.f;
        const float b = (k0 + 1 < K && n < N) ? W[(size_t)(k0 + 1) * N + n] : 0.f;
        u[p] = pk2(a, b);
    }
    wf[base + f * 64 + l] = make_uint4(u[0], u[1], u[2], u[3]);
}

__global__ __launch_bounds__(THREADS, 2)   // cap 256: the only no-spill regime
void ar_gas_v25(const float* __restrict__ x,
                const float* __restrict__ last_mu,
                const float* __restrict__ last_sigma,
                const float* __restrict__ p_amu, const float* __restrict__ p_as,
                const float* __restrict__ p_bmu, const float* __restrict__ p_bs,
                const float* __restrict__ p_omu, const float* __restrict__ p_os,
                const float* __restrict__ p_nu,  const float* __restrict__ p_ns,
                const float* __restrict__ b1, const float* __restrict__ b2,
                const float* __restrict__ b3,
                const uint4* __restrict__ wf,
                float* __restrict__ out)
{
    extern __shared__ __align__(16) unsigned char L[];
    const int tid  = threadIdx.x;
    const int lane = tid & 63;
    const int wid  = tid >> 6;
    const int l15  = lane & 15;
    const int l4   = lane >> 4;
    const int blk  = blockIdx.x;

    // GAS scalars (uniform)
    const float anu = *p_nu,  ans = *p_ns;
    const float aMu = *p_amu, aSg = *p_as;
    const float bMu = *p_bmu, bSg = *p_bs;
    const float oMu = *p_omu, oSg = *p_os;
    const float wS  = 1.f + __builtin_amdgcn_rcpf(anu);
    const float cmu = ans * aMu * wS;
    const float cs  = ans * aSg * wS;
    const float bs2 = bSg - ans * aSg;

#define XLOADT(dst, base_row, kk)                                       \
    { int kb = (kk) * 32 + l4 * 8;                                      \
      kb = (kb + 8 <= 200) ? kb : 168;   /* clamp x zero-pad W1 = 0 */  \
      const float* p_ = x + ((base_row) + l15) * 200;                   \
      dst[kk][0] = *(const float4*)(p_ + kb);                           \
      dst[kk][1] = *(const float4*)(p_ + kb + 4); }

    // wave rows: [gw0, gw0+128), tile t rows gw0 + t*16
    const size_t gw0 = (size_t)blk * BMROWS + (size_t)wid * (16 * NTILES);

    // ---- prologue burst: X(tile0) into 56 VGPRs + all 93 frags -> LDS ----
    float4 xv[7][2];
    #pragma unroll
    for (int kc = 0; kc < 7; ++kc) XLOADT(xv, gw0, kc);

    for (int s = wid; s < 93; s += WAVES)
        gload_lds16(wf + s * 64 + lane, L + s * 1024);
    __syncthreads();   // THE only barrier: X in regs, all frags resident

    // ---- wave-gradient phase stagger (r22: +1.6%) ----
    for (int i = 0; i < wid; ++i) __builtin_amdgcn_s_sleep(7);

#define FRAG_W1(f)  (*(const uint4*)(&L[(W1F + (f)) * 1024 + lane * 16]))
#define FRAG_W2(f)  (*(const uint4*)(&L[(W2F + (f)) * 1024 + lane * 16]))
#define FRAG_W3(f)  (*(const uint4*)(&L[(W3F + (f)) * 1024 + lane * 16]))

    // affine slab bases (all ds offsets are compile-time constants)
    const int sb      = SLABB + wid * SLAB_SIZE;
    const int sb_epi  = sb + (l4 * 4) * SLAB_STRIDE + l15 * 2;  // +r*264+nt*32
    const int sb_rd   = sb + l15 * SLAB_STRIDE + l4 * 16;       // +kc*64
    const int sb_dpw  = sb + (l4 * 4) * SLAB_STRIDE + l15 * 4;  // +r*264+nt*64
    const int sb_gas  = sb + (lane * 4) * SLAB_STRIDE;          // lane<4: 4 rows
    const int sb_st   = sb + l4 * SLAB_STRIDE + l15 * 16;       // +i*1056

    #pragma unroll 1
    for (int t = 0; t < NTILES; ++t) {
        const size_t gw = gw0 + t * 16;

        // GAS state: lane<4 owns rows lane*4..lane*4+3 (float4 loads, 4 rows)
        float4 mu4 = make_float4(0.f, 0.f, 0.f, 0.f);
        float4 s24 = make_float4(1.f, 1.f, 1.f, 1.f);
        if (lane < 4) {
            mu4 = *(const float4*)(last_mu    + gw + lane * 4);
            s24 = *(const float4*)(last_sigma + gw + lane * 4);
        }

        // ================= layer 1: h1 = relu(X @ W1 + b1) ==============
        v4f acc[7];
        #pragma unroll
        for (int nt = 0; nt < 7; ++nt) acc[nt] = (v4f){0.f, 0.f, 0.f, 0.f};
        #pragma unroll
        for (int kc = 0; kc < 7; ++kc) {
            uint4 bu[7];
            #pragma unroll
            for (int nt = 0; nt < 7; ++nt) bu[nt] = FRAG_W1(nt * 7 + kc);
            const v8s af = mkfrag(xv[kc][0], xv[kc][1]);   // regs only
            #pragma unroll
            for (int nt = 0; nt < 7; ++nt)
                acc[nt] = mfma16(af, *(const v8s*)&bu[nt], acc[nt]);
        }

        // xv dead: issue NEXT tile's X loads; stream in under epi/L2/L3/GAS
        if (t < NTILES - 1) {
            #pragma unroll
            for (int kc = 0; kc < 7; ++kc) XLOADT(xv, gw0 + (t + 1) * 16, kc);
        }

        // epilogue -> slab (bf16 [16 rows][stride 264]); transient bias
        {
            float bv[7];
            #pragma unroll
            for (int nt = 0; nt < 7; ++nt) {
                const int c = nt * 16 + l15;
                bv[nt] = (c < 100) ? b1[c] : 0.f;
            }
            #pragma unroll
            for (int nt = 0; nt < 7; ++nt)
                #pragma unroll
                for (int r = 0; r < 4; ++r) {
                    const float v = fmaxf(acc[nt][r] + bv[nt], 0.f);
                    *(unsigned short*)(&L[sb_epi + r * SLAB_STRIDE + nt * 32]) =
                        f2bf(v);
                }
        }
        // zero cols 112..127 (100..111 zero via zero-padded frags)
        if (lane < 32)
            *(uint4*)(&L[sb + (lane >> 1) * SLAB_STRIDE + 224 + (lane & 1) * 16]) =
                make_uint4(0, 0, 0, 0);

        // ================= layer 2: h2 = relu(h1 @ W2 + b2) =============
        v4f acc2[7];
        #pragma unroll
        for (int nt = 0; nt < 7; ++nt) acc2[nt] = (v4f){0.f, 0.f, 0.f, 0.f};
        #pragma unroll
        for (int kc = 0; kc < 4; ++kc) {
            uint4 bu[7];
            #pragma unroll
            for (int nt = 0; nt < 7; ++nt) bu[nt] = FRAG_W2(nt * 4 + kc);
            uint4 t0 = *(const uint4*)(&L[sb_rd + kc * 64]);
            const v8s af = *(v8s*)&t0;
            #pragma unroll
            for (int nt = 0; nt < 7; ++nt)
                acc2[nt] = mfma16(af, *(const v8s*)&bu[nt], acc2[nt]);
        }
        // h2 overwrites h1 in-place (in-wave DS ordering); pads keep zeros
        {
            float bv[7];
            #pragma unroll
            for (int nt = 0; nt < 7; ++nt) {
                const int c = nt * 16 + l15;
                bv[nt] = (c < 100) ? b2[c] : 0.f;
            }
            #pragma unroll
            for (int nt = 0; nt < 7; ++nt)
                #pragma unroll
                for (int r = 0; r < 4; ++r) {
                    const float v = fmaxf(acc2[nt][r] + bv[nt], 0.f);
                    *(unsigned short*)(&L[sb_epi + r * SLAB_STRIDE + nt * 32]) =
                        f2bf(v);
                }
        }

        // ================= layer 3: DP = h2 @ W3 + b3 ===================
        v4f acc3[4];
        #pragma unroll
        for (int nt = 0; nt < 4; ++nt) acc3[nt] = (v4f){0.f, 0.f, 0.f, 0.f};
        #pragma unroll
        for (int kc = 0; kc < 4; ++kc) {
            uint4 bu[4];
            #pragma unroll
            for (int nt = 0; nt < 4; ++nt) bu[nt] = FRAG_W3(nt * 4 + kc);
            uint4 t0 = *(const uint4*)(&L[sb_rd + kc * 64]);
            const v8s af = *(v8s*)&t0;
            #pragma unroll
            for (int nt = 0; nt < 4; ++nt)
                acc3[nt] = mfma16(af, *(const v8s*)&bu[nt], acc3[nt]);
        }
        // DP (f32 [16][64]) overwrites slab (h2 reads precede in program order)
        {
            float bv[4];
            #pragma unroll
            for (int nt = 0; nt < 4; ++nt) bv[nt] = b3[nt * 16 + l15];
            #pragma unroll
            for (int nt = 0; nt < 4; ++nt)
                #pragma unroll
                for (int r = 0; r < 4; ++r)
                    *(float*)(&L[sb_dpw + r * SLAB_STRIDE + nt * 64]) =
                        acc3[nt][r] + bv[nt];
        }

        // ====== GAS: lane<4 x 4 rows each -> 4 independent chains/lane ===
        // Chain duration is latency-bound (~36 cyc/step); 4-way ILP per
        // lane hides ~3/4 of it (the r24 batching idea, done in LDS).
        if (lane < 4) {
            float mu[4] = { mu4.x, mu4.y, mu4.z, mu4.w };
            float s2[4] = { s24.x, s24.y, s24.z, s24.w };
#define GAS_STEP(J, Y, O)                                               \
            {   const float e    = (Y) - mu[J];                         \
                const float nus2 = anu * s2[J];                         \
                const float den  = fmaf(e, e, nus2);                    \
                const float r0   = __builtin_amdgcn_rcpf(den);          \
                const float p    = e * nus2 * r0;                       \
                mu[J] = fmaf(cmu, p, fmaf(bMu, mu[J], oMu));            \
                s2[J] = fmaf(cs, e * p, fmaf(bs2, s2[J], oSg));         \
                (O) = fmaf((Y), __builtin_amdgcn_sqrtf(s2[J]), mu[J]); }
            #pragma unroll
            for (int q = 0; q < 16; ++q) {
                float4 d0 = *(float4*)(&L[sb_gas + 0 * SLAB_STRIDE + q * 16]);
                float4 d1 = *(float4*)(&L[sb_gas + 1 * SLAB_STRIDE + q * 16]);
                float4 d2 = *(float4*)(&L[sb_gas + 2 * SLAB_STRIDE + q * 16]);
                float4 d3 = *(float4*)(&L[sb_gas + 3 * SLAB_STRIDE + q * 16]);
                float4 o0, o1, o2, o3;
                GAS_STEP(0, d0.x, o0.x); GAS_STEP(1, d1.x, o1.x);
                GAS_STEP(2, d2.x, o2.x); GAS_STEP(3, d3.x, o3.x);
                GAS_STEP(0, d0.y, o0.y); GAS_STEP(1, d1.y, o1.y);
                GAS_STEP(2, d2.y, o2.y); GAS_STEP(3, d3.y, o3.y);
                GAS_STEP(0, d0.z, o0.z); GAS_STEP(1, d1.z, o1.z);
                GAS_STEP(2, d2.z, o2.z); GAS_STEP(3, d3.z, o3.z);
                GAS_STEP(0, d0.w, o0.w); GAS_STEP(1, d1.w, o1.w);
                GAS_STEP(2, d2.w, o2.w); GAS_STEP(3, d3.w, o3.w);
                *(float4*)(&L[sb_gas + 0 * SLAB_STRIDE + q * 16]) = o0;
                *(float4*)(&L[sb_gas + 1 * SLAB_STRIDE + q * 16]) = o1;
                *(float4*)(&L[sb_gas + 2 * SLAB_STRIDE + q * 16]) = o2;
                *(float4*)(&L[sb_gas + 3 * SLAB_STRIDE + q * 16]) = o3;
            }
#undef GAS_STEP
        }

        // ============ wave-wide coalesced float4 store (no barrier) =======
        #pragma unroll
        for (int i = 0; i < 4; ++i) {
            float4 v = *(float4*)(&L[sb_st + i * (4 * SLAB_STRIDE)]);
            ((float4*)out)[gw * 16 + i * 64 + lane] = v;
        }
    }
#undef FRAG_W1
#undef FRAG_W2
#undef FRAG_W3
#undef XLOADT
}

extern "C" void kernel_launch(void* const* d_in, const int* in_sizes, int n_in,
                              void* d_out, int out_size, void* d_ws, size_t ws_size,
                              hipStream_t stream) {
    const float* x          = (const float*)d_in[0];
    const float* last_mu    = (const float*)d_in[1];
    const float* last_sigma = (const float*)d_in[2];
    const float* amu        = (const float*)d_in[3];
    const float* asig       = (const float*)d_in[4];
    const float* bmu        = (const float*)d_in[5];
    const float* bsig       = (const float*)d_in[6];
    const float* omu        = (const float*)d_in[7];
    const float* osig       = (const float*)d_in[8];
    const float* nu         = (const float*)d_in[9];
    const float* ns         = (const float*)d_in[10];
    const float* W1         = (const float*)d_in[11];
    const float* b1         = (const float*)d_in[12];
    const float* W2         = (const float*)d_in[13];
    const float* b2         = (const float*)d_in[14];
    const float* W3         = (const float*)d_in[15];
    const float* b3         = (const float*)d_in[16];
    float* out = (float*)d_out;

    uint4* wf = (uint4*)d_ws;   // 95,232 B fragment table (93 frags)
    prep_weights<<<93, 64, 0, stream>>>(W1, W2, W3, wf);

    hipFuncSetAttribute((const void*)ar_gas_v25,
                        hipFuncAttributeMaxDynamicSharedMemorySize, LDS_TOTAL);

    const int B = in_sizes[1];                 // 262144
    dim3 grid(B / BMROWS), block(THREADS);     // 256 blocks = 1 per CU
    ar_gas_v25<<<grid, block, LDS_TOTAL, stream>>>(
        x, last_mu, last_sigma,
        amu, asig, bmu, bsig, omu, osig, nu, ns,
        b1, b2, b3, wf, out);
}

// Round 26
// 77.388 us; speedup vs baseline: 2.1972x; 2.1972x over previous
//
#include <hip/hip_runtime.h>
#include <hip/hip_bf16.h>

typedef short v8s __attribute__((ext_vector_type(8)));
typedef float v4f __attribute__((ext_vector_type(4)));

#define THREADS 512      // 8 waves; each wave: 8 tiles x 16 rows = 128 rows
#define WAVES   8
#define NTILES  8
#define BMROWS  1024     // rows per block -> grid = 256 = exactly 1 block/CU
// d_ws frag order: W1 0-48, W2 49-76, W3 77-92 (slot s at LDS s*1024)
#define W1F     0
#define W2F     49
#define W3F     77
#define SLABB   95232                    // 93 frag slots end here
#define SLAB_STRIDE 264
#define REGSZ   4224                     // 16 rows * 264
#define SLAB_SIZE   (2 * REGSZ)          // region A (h+DP-odd) + region B (DP-even)
#define LDS_TOTAL   (SLABB + WAVES * SLAB_SIZE)   // 162,816 <= 163,840

__device__ __forceinline__ unsigned short f2bf(float f) {
    union { __hip_bfloat16 h; unsigned short u; } c;
    c.h = __float2bfloat16(f);
    return c.u;
}
__device__ __forceinline__ unsigned pk2(float a, float b) {
    return (unsigned)f2bf(a) | ((unsigned)f2bf(b) << 16);
}
__device__ __forceinline__ v4f mfma16(v8s a, v8s b, v4f c) {
    return __builtin_amdgcn_mfma_f32_16x16x32_bf16(a, b, c, 0, 0, 0);
}
__device__ __forceinline__ v8s mkfrag(float4 a, float4 b) {
    union { unsigned u[4]; v8s s; } t;
    t.u[0] = pk2(a.x, a.y); t.u[1] = pk2(a.z, a.w);
    t.u[2] = pk2(b.x, b.y); t.u[3] = pk2(b.z, b.w);
    return t.s;
}
__device__ __forceinline__ void gload_lds16(const void* g, void* l) {
    __builtin_amdgcn_global_load_lds(
        (const __attribute__((address_space(1))) void*)g,
        (__attribute__((address_space(3))) void*)l, 16, 0, 0);
}

// ---- prep: weights -> MFMA B-fragment layout (bf16, zero-padded) ----------
// frag(nt,kc): lane l holds B[k = kc*32+(l>>4)*8+j][n = nt*16+(l&15)], j=0..7
__global__ void prep_weights(const float* __restrict__ W1,
                             const float* __restrict__ W2,
                             const float* __restrict__ W3,
                             uint4* __restrict__ wf) {
    const int bid = blockIdx.x, l = threadIdx.x;
    const float* W; int K, N, KC, base, f;
    if (bid < 49)      { W = W1; K = 200; N = 100; KC = 7; base = W1F * 64; f = bid; }
    else if (bid < 77) { W = W2; K = 100; N = 100; KC = 4; base = W2F * 64; f = bid - 49; }
    else               { W = W3; K = 100; N = 64;  KC = 4; base = W3F * 64; f = bid - 77; }
    const int kc = f % KC;
    const int n  = (f / KC) * 16 + (l & 15);
    unsigned u[4];
    #pragma unroll
    for (int p = 0; p < 4; ++p) {
        const int k0 = kc * 32 + (l >> 4) * 8 + p * 2;
        const float a = (k0     < K && n < N) ? W[(size_t)k0 * N + n]       : 0.f;
        const float b = (k0 + 1 < K && n < N) ? W[(size_t)(k0 + 1) * N + n] : 0.f;
        u[p] = pk2(a, b);
    }
    wf[base + f * 64 + l] = make_uint4(u[0], u[1], u[2], u[3]);
}

__global__ __launch_bounds__(THREADS, 2)   // cap 256: the only no-spill regime
void ar_gas_v26(const float* __restrict__ x,
                const float* __restrict__ last_mu,
                const float* __restrict__ last_sigma,
                const float* __restrict__ p_amu, const float* __restrict__ p_as,
                const float* __restrict__ p_bmu, const float* __restrict__ p_bs,
                const float* __restrict__ p_omu, const float* __restrict__ p_os,
                const float* __restrict__ p_nu,  const float* __restrict__ p_ns,
                const float* __restrict__ b1, const float* __restrict__ b2,
                const float* __restrict__ b3,
                const uint4* __restrict__ wf,
                float* __restrict__ out)
{
    extern __shared__ __align__(16) unsigned char L[];
    const int tid  = threadIdx.x;
    const int lane = tid & 63;
    const int wid  = tid >> 6;
    const int l15  = lane & 15;
    const int l4   = lane >> 4;
    const int blk  = blockIdx.x;

    // GAS scalars (uniform)
    const float anu = *p_nu,  ans = *p_ns;
    const float aMu = *p_amu, aSg = *p_as;
    const float bMu = *p_bmu, bSg = *p_bs;
    const float oMu = *p_omu, oSg = *p_os;
    const float wS  = 1.f + __builtin_amdgcn_rcpf(anu);
    const float cmu = ans * aMu * wS;
    const float cs  = ans * aSg * wS;
    const float bs2 = bSg - ans * aSg;

#define XLOADT(dst, base_row, kk)                                       \
    { int kb = (kk) * 32 + l4 * 8;                                      \
      kb = (kb + 8 <= 200) ? kb : 168;   /* clamp x zero-pad W1 = 0 */  \
      const float* p_ = x + ((base_row) + l15) * 200;                   \
      dst[kk][0] = *(const float4*)(p_ + kb);                           \
      dst[kk][1] = *(const float4*)(p_ + kb + 4); }

    // wave rows: [gw0, gw0+128), tile t rows gw0 + t*16
    const size_t gw0 = (size_t)blk * BMROWS + (size_t)wid * (16 * NTILES);

    // ---- prologue burst: X(tile0) into 56 VGPRs + all 93 frags -> LDS ----
    float4 xv[7][2];
    #pragma unroll
    for (int kc = 0; kc < 7; ++kc) XLOADT(xv, gw0, kc);

    for (int s = wid; s < 93; s += WAVES)
        gload_lds16(wf + s * 64 + lane, L + s * 1024);
    __syncthreads();   // THE only barrier: X in regs, all frags resident

    // ---- wave-gradient phase stagger (r22: +1.6%) ----
    for (int i = 0; i < wid; ++i) __builtin_amdgcn_s_sleep(7);

#define FRAG_W1(f)  (*(const uint4*)(&L[(W1F + (f)) * 1024 + lane * 16]))
#define FRAG_W2(f)  (*(const uint4*)(&L[(W2F + (f)) * 1024 + lane * 16]))
#define FRAG_W3(f)  (*(const uint4*)(&L[(W3F + (f)) * 1024 + lane * 16]))

    // region A = h1/h2 + DP(odd tile); region B = DP(even tile)
    const int sb      = SLABB + wid * SLAB_SIZE;        // region A base
    const int sbB     = sb + REGSZ;                      // region B base
    const int sb_epi  = sb + (l4 * 4) * SLAB_STRIDE + l15 * 2;  // +r*264+nt*32
    const int sb_rd   = sb + l15 * SLAB_STRIDE + l4 * 16;       // +kc*64
    const int dp_off  = (l4 * 4) * SLAB_STRIDE + l15 * 4;       // +r*264+nt*64
    const int st_off  = l4 * SLAB_STRIDE + l15 * 16;            // +i*1056
    // GAS (32 lanes): lanes 0-15 -> region B rows (even tile),
    //                 lanes 16-31 -> region A rows (odd tile)
    const int gas_base = ((lane < 16) ? sbB : sb) + l15 * SLAB_STRIDE;

    float mu_i = 0.f, s2_i = 1.f;

    #pragma unroll 1
    for (int t = 0; t < NTILES; ++t) {
        const size_t gw = gw0 + t * 16;
        const bool even = ((t & 1) == 0);
        const int  dpb  = (even ? sbB : sb) + dp_off;

        // pair start: lane<32 loads state for BOTH tiles of the pair
        if (even && lane < 32) {
            mu_i = last_mu[gw + lane];
            s2_i = last_sigma[gw + lane];
        }

        // ================= layer 1: h1 = relu(X @ W1 + b1) ==============
        v4f acc[7];
        #pragma unroll
        for (int nt = 0; nt < 7; ++nt) acc[nt] = (v4f){0.f, 0.f, 0.f, 0.f};
        #pragma unroll
        for (int kc = 0; kc < 7; ++kc) {
            uint4 bu[7];
            #pragma unroll
            for (int nt = 0; nt < 7; ++nt) bu[nt] = FRAG_W1(nt * 7 + kc);
            const v8s af = mkfrag(xv[kc][0], xv[kc][1]);   // regs only
            #pragma unroll
            for (int nt = 0; nt < 7; ++nt)
                acc[nt] = mfma16(af, *(const v8s*)&bu[nt], acc[nt]);
        }

        // xv dead: issue NEXT tile's X loads; stream in under compute
        if (t < NTILES - 1) {
            #pragma unroll
            for (int kc = 0; kc < 7; ++kc) XLOADT(xv, gw0 + (t + 1) * 16, kc);
        }

        // epilogue -> region A (bf16 [16 rows][stride 264]); transient bias
        {
            float bv[7];
            #pragma unroll
            for (int nt = 0; nt < 7; ++nt) {
                const int c = nt * 16 + l15;
                bv[nt] = (c < 100) ? b1[c] : 0.f;
            }
            #pragma unroll
            for (int nt = 0; nt < 7; ++nt)
                #pragma unroll
                for (int r = 0; r < 4; ++r) {
                    const float v = fmaxf(acc[nt][r] + bv[nt], 0.f);
                    *(unsigned short*)(&L[sb_epi + r * SLAB_STRIDE + nt * 32]) =
                        f2bf(v);
                }
        }
        // zero cols 112..127 (100..111 zero via zero-padded frags)
        if (lane < 32)
            *(uint4*)(&L[sb + (lane >> 1) * SLAB_STRIDE + 224 + (lane & 1) * 16]) =
                make_uint4(0, 0, 0, 0);

        // ================= layer 2: h2 = relu(h1 @ W2 + b2) =============
        v4f acc2[7];
        #pragma unroll
        for (int nt = 0; nt < 7; ++nt) acc2[nt] = (v4f){0.f, 0.f, 0.f, 0.f};
        #pragma unroll
        for (int kc = 0; kc < 4; ++kc) {
            uint4 bu[7];
            #pragma unroll
            for (int nt = 0; nt < 7; ++nt) bu[nt] = FRAG_W2(nt * 4 + kc);
            uint4 t0 = *(const uint4*)(&L[sb_rd + kc * 64]);
            const v8s af = *(v8s*)&t0;
            #pragma unroll
            for (int nt = 0; nt < 7; ++nt)
                acc2[nt] = mfma16(af, *(const v8s*)&bu[nt], acc2[nt]);
        }
        // h2 overwrites h1 in-place (in-wave DS ordering); pads keep zeros
        {
            float bv[7];
            #pragma unroll
            for (int nt = 0; nt < 7; ++nt) {
                const int c = nt * 16 + l15;
                bv[nt] = (c < 100) ? b2[c] : 0.f;
            }
            #pragma unroll
            for (int nt = 0; nt < 7; ++nt)
                #pragma unroll
                for (int r = 0; r < 4; ++r) {
                    const float v = fmaxf(acc2[nt][r] + bv[nt], 0.f);
                    *(unsigned short*)(&L[sb_epi + r * SLAB_STRIDE + nt * 32]) =
                        f2bf(v);
                }
        }

        // ================= layer 3: DP = h2 @ W3 + b3 ===================
        v4f acc3[4];
        #pragma unroll
        for (int nt = 0; nt < 4; ++nt) acc3[nt] = (v4f){0.f, 0.f, 0.f, 0.f};
        #pragma unroll
        for (int kc = 0; kc < 4; ++kc) {
            uint4 bu[4];
            #pragma unroll
            for (int nt = 0; nt < 4; ++nt) bu[nt] = FRAG_W3(nt * 4 + kc);
            uint4 t0 = *(const uint4*)(&L[sb_rd + kc * 64]);
            const v8s af = *(v8s*)&t0;
            #pragma unroll
            for (int nt = 0; nt < 4; ++nt)
                acc3[nt] = mfma16(af, *(const v8s*)&bu[nt], acc3[nt]);
        }
        // DP -> region B (even tile) or region A (odd tile, overwrites h2)
        {
            float bv[4];
            #pragma unroll
            for (int nt = 0; nt < 4; ++nt) bv[nt] = b3[nt * 16 + l15];
            #pragma unroll
            for (int nt = 0; nt < 4; ++nt)
                #pragma unroll
                for (int r = 0; r < 4; ++r)
                    *(float*)(&L[dpb + r * SLAB_STRIDE + nt * 64]) =
                        acc3[nt][r] + bv[nt];
        }

        // ====== pair complete (odd t): GAS on 32 lanes, then 2 stores =====
        // Same per-lane instruction count as v23 (one chain per lane), but
        // 2x rows per phase -> half the latency-bound GAS phases.
        if (!even) {
            if (lane < 32) {
                float mu = mu_i;
                float s2 = s2_i;
#define GAS_STEP(Y, O)                                                  \
                {   const float e    = (Y) - mu;                        \
                    const float nus2 = anu * s2;                        \
                    const float den  = fmaf(e, e, nus2);                \
                    const float r0   = __builtin_amdgcn_rcpf(den);      \
                    const float p    = e * nus2 * r0;                   \
                    mu = fmaf(cmu, p, fmaf(bMu, mu, oMu));              \
                    s2 = fmaf(cs, e * p, fmaf(bs2, s2, oSg));           \
                    (O) = fmaf((Y), __builtin_amdgcn_sqrtf(s2), mu); }
                #pragma unroll
                for (int q = 0; q < 16; ++q) {
                    float4 d = *(float4*)(&L[gas_base + q * 16]);
                    float o0, o1, o2, o3;
                    GAS_STEP(d.x, o0); GAS_STEP(d.y, o1);
                    GAS_STEP(d.z, o2); GAS_STEP(d.w, o3);
                    *(float4*)(&L[gas_base + q * 16]) =
                        make_float4(o0, o1, o2, o3);
                }
#undef GAS_STEP
            }
            // store even tile (region B) then odd tile (region A)
            const size_t gwe = gw - 16;
            #pragma unroll
            for (int i = 0; i < 4; ++i) {
                float4 v = *(float4*)(&L[sbB + st_off + i * (4 * SLAB_STRIDE)]);
                ((float4*)out)[gwe * 16 + i * 64 + lane] = v;
            }
            #pragma unroll
            for (int i = 0; i < 4; ++i) {
                float4 v = *(float4*)(&L[sb + st_off + i * (4 * SLAB_STRIDE)]);
                ((float4*)out)[gw * 16 + i * 64 + lane] = v;
            }
        }
    }
#undef FRAG_W1
#undef FRAG_W2
#undef FRAG_W3
#undef XLOADT
}

extern "C" void kernel_launch(void* const* d_in, const int* in_sizes, int n_in,
                              void* d_out, int out_size, void* d_ws, size_t ws_size,
                              hipStream_t stream) {
    const float* x          = (const float*)d_in[0];
    const float* last_mu    = (const float*)d_in[1];
    const float* last_sigma = (const float*)d_in[2];
    const float* amu        = (const float*)d_in[3];
    const float* asig       = (const float*)d_in[4];
    const float* bmu        = (const float*)d_in[5];
    const float* bsig       = (const float*)d_in[6];
    const float* omu        = (const float*)d_in[7];
    const float* osig       = (const float*)d_in[8];
    const float* nu         = (const float*)d_in[9];
    const float* ns         = (const float*)d_in[10];
    const float* W1         = (const float*)d_in[11];
    const float* b1         = (const float*)d_in[12];
    const float* W2         = (const float*)d_in[13];
    const float* b2         = (const float*)d_in[14];
    const float* W3         = (const float*)d_in[15];
    const float* b3         = (const float*)d_in[16];
    float* out = (float*)d_out;

    uint4* wf = (uint4*)d_ws;   // 95,232 B fragment table (93 frags)
    prep_weights<<<93, 64, 0, stream>>>(W1, W2, W3, wf);

    hipFuncSetAttribute((const void*)ar_gas_v26,
                        hipFuncAttributeMaxDynamicSharedMemorySize, LDS_TOTAL);

    const int B = in_sizes[1];                 // 262144
    dim3 grid(B / BMROWS), block(THREADS);     // 256 blocks = 1 per CU
    ar_gas_v26<<<grid, block, LDS_TOTAL, stream>>>(
        x, last_mu, last_sigma,
        amu, asig, bmu, bsig, omu, osig, nu, ns,
        b1, b2, b3, wf, out);
}

// Round 27
// 75.935 us; speedup vs baseline: 2.2392x; 1.0191x over previous
//
#include <hip/hip_runtime.h>
#include <hip/hip_bf16.h>

typedef short v8s __attribute__((ext_vector_type(8)));
typedef float v4f __attribute__((ext_vector_type(4)));

#define THREADS 512      // 8 waves; each wave: 8 tiles x 16 rows = 128 rows
#define WAVES   8
#define NTILES  8
#define BMROWS  1024     // rows per block -> grid = 256 = exactly 1 block/CU
// d_ws frag order: W1 0-48, W2 49-76, W3 77-92 (slot s at LDS s*1024)
#define W1F     0
#define W2F     49
#define W3F     77
#define SLABB   95232                    // 93 frag slots end here
#define SLAB_STRIDE 264
#define SLAB_SIZE   4224                 // 16 rows * 264
#define LDS_TOTAL   (SLABB + WAVES * SLAB_SIZE)   // 129,024 B -> 1 block/CU

__device__ __forceinline__ unsigned short f2bf(float f) {
    union { __hip_bfloat16 h; unsigned short u; } c;
    c.h = __float2bfloat16(f);
    return c.u;
}
__device__ __forceinline__ unsigned pk2(float a, float b) {
    return (unsigned)f2bf(a) | ((unsigned)f2bf(b) << 16);
}
__device__ __forceinline__ v4f mfma16(v8s a, v8s b, v4f c) {
    return __builtin_amdgcn_mfma_f32_16x16x32_bf16(a, b, c, 0, 0, 0);
}
__device__ __forceinline__ v8s mkfrag(float4 a, float4 b) {
    union { unsigned u[4]; v8s s; } t;
    t.u[0] = pk2(a.x, a.y); t.u[1] = pk2(a.z, a.w);
    t.u[2] = pk2(b.x, b.y); t.u[3] = pk2(b.z, b.w);
    return t.s;
}
__device__ __forceinline__ void gload_lds16(const void* g, void* l) {
    __builtin_amdgcn_global_load_lds(
        (const __attribute__((address_space(1))) void*)g,
        (__attribute__((address_space(3))) void*)l, 16, 0, 0);
}

// ---- prep: weights -> MFMA B-fragment layout (bf16, zero-padded) ----------
// frag(nt,kc): lane l holds B[k = kc*32+(l>>4)*8+j][n = nt*16+(l&15)], j=0..7
__global__ void prep_weights(const float* __restrict__ W1,
                             const float* __restrict__ W2,
                             const float* __restrict__ W3,
                             uint4* __restrict__ wf) {
    const int bid = blockIdx.x, l = threadIdx.x;
    const float* W; int K, N, KC, base, f;
    if (bid < 49)      { W = W1; K = 200; N = 100; KC = 7; base = W1F * 64; f = bid; }
    else if (bid < 77) { W = W2; K = 100; N = 100; KC = 4; base = W2F * 64; f = bid - 49; }
    else               { W = W3; K = 100; N = 64;  KC = 4; base = W3F * 64; f = bid - 77; }
    const int kc = f % KC;
    const int n  = (f / KC) * 16 + (l & 15);
    unsigned u[4];
    #pragma unroll
    for (int p = 0; p < 4; ++p) {
        const int k0 = kc * 32 + (l >> 4) * 8 + p * 2;
        const float a = (k0     < K && n < N) ? W[(size_t)k0 * N + n]       : 0.f;
        const float b = (k0 + 1 < K && n < N) ? W[(size_t)(k0 + 1) * N + n] : 0.f;
        u[p] = pk2(a, b);
    }
    wf[base + f * 64 + l] = make_uint4(u[0], u[1], u[2], u[3]);
}

__global__ __launch_bounds__(THREADS, 2)   // cap 256: the only no-spill regime
void ar_gas_v23(const float* __restrict__ x,
                const float* __restrict__ last_mu,
                const float* __restrict__ last_sigma,
                const float* __restrict__ p_amu, const float* __restrict__ p_as,
                const float* __restrict__ p_bmu, const float* __restrict__ p_bs,
                const float* __restrict__ p_omu, const float* __restrict__ p_os,
                const float* __restrict__ p_nu,  const float* __restrict__ p_ns,
                const float* __restrict__ b1, const float* __restrict__ b2,
                const float* __restrict__ b3,
                const uint4* __restrict__ wf,
                float* __restrict__ out)
{
    extern __shared__ __align__(16) unsigned char L[];
    const int tid  = threadIdx.x;
    const int lane = tid & 63;
    const int wid  = tid >> 6;
    const int l15  = lane & 15;
    const int l4   = lane >> 4;
    const int blk  = blockIdx.x;

    // GAS scalars (uniform)
    const float anu = *p_nu,  ans = *p_ns;
    const float aMu = *p_amu, aSg = *p_as;
    const float bMu = *p_bmu, bSg = *p_bs;
    const float oMu = *p_omu, oSg = *p_os;
    const float wS  = 1.f + __builtin_amdgcn_rcpf(anu);
    const float cmu = ans * aMu * wS;
    const float cs  = ans * aSg * wS;
    const float bs2 = bSg - ans * aSg;

#define XLOADT(dst, base_row, kk)                                       \
    { int kb = (kk) * 32 + l4 * 8;                                      \
      kb = (kb + 8 <= 200) ? kb : 168;   /* clamp x zero-pad W1 = 0 */  \
      const float* p_ = x + ((base_row) + l15) * 200;                   \
      dst[kk][0] = *(const float4*)(p_ + kb);                           \
      dst[kk][1] = *(const float4*)(p_ + kb + 4); }

    // wave rows: [gw0, gw0+128), tile t rows gw0 + t*16
    const size_t gw0 = (size_t)blk * BMROWS + (size_t)wid * (16 * NTILES);

    // ---- prologue burst: X(tile0) into 56 VGPRs + all 93 frags -> LDS ----
    float4 xv[7][2];
    #pragma unroll
    for (int kc = 0; kc < 7; ++kc) XLOADT(xv, gw0, kc);

    for (int s = wid; s < 93; s += WAVES)
        gload_lds16(wf + s * 64 + lane, L + s * 1024);
    __syncthreads();   // THE only barrier: X in regs, all frags resident

    // ---- wave-gradient phase stagger (de-phase SIMD siblings; r22 +1.6%) ----
    for (int i = 0; i < wid; ++i) __builtin_amdgcn_s_sleep(7);

#define FRAG_W1(f)  (*(const uint4*)(&L[(W1F + (f)) * 1024 + lane * 16]))
#define FRAG_W2(f)  (*(const uint4*)(&L[(W2F + (f)) * 1024 + lane * 16]))
#define FRAG_W3(f)  (*(const uint4*)(&L[(W3F + (f)) * 1024 + lane * 16]))

    // affine slab bases (all ds offsets are compile-time constants)
    const int sb      = SLABB + wid * SLAB_SIZE;
    const int sb_epi  = sb + (l4 * 4) * SLAB_STRIDE + l15 * 2;  // +r*264+nt*32
    const int sb_rd   = sb + l15 * SLAB_STRIDE + l4 * 16;       // +kc*64
    const int sb_dpw  = sb + (l4 * 4) * SLAB_STRIDE + l15 * 4;  // +r*264+nt*64
    const int sb_gas  = sb + l15 * SLAB_STRIDE;                 // +q*16
    const int sb_st   = sb + l4 * SLAB_STRIDE + l15 * 16;       // +i*1056

    #pragma unroll 1
    for (int t = 0; t < NTILES; ++t) {
        const size_t gw = gw0 + t * 16;

        // state loads now; consumed at GAS ~6K cyc later
        const float mu_init = last_mu[gw + l15];
        const float s2_init = last_sigma[gw + l15];

        // ================= layer 1: h1 = relu(X @ W1 + b1) ==============
        v4f acc[7];
        #pragma unroll
        for (int nt = 0; nt < 7; ++nt) acc[nt] = (v4f){0.f, 0.f, 0.f, 0.f};
        #pragma unroll
        for (int kc = 0; kc < 7; ++kc) {
            uint4 bu[7];
            #pragma unroll
            for (int nt = 0; nt < 7; ++nt) bu[nt] = FRAG_W1(nt * 7 + kc);
            const v8s af = mkfrag(xv[kc][0], xv[kc][1]);   // regs only
            #pragma unroll
            for (int nt = 0; nt < 7; ++nt)
                acc[nt] = mfma16(af, *(const v8s*)&bu[nt], acc[nt]);
        }

        // xv dead: issue NEXT tile's X loads; stream in under epi/L2/L3/GAS
        if (t < NTILES - 1) {
            #pragma unroll
            for (int kc = 0; kc < 7; ++kc) XLOADT(xv, gw0 + (t + 1) * 16, kc);
        }

        // epilogue -> slab (bf16 [16 rows][stride 264]); transient bias
        {
            float bv[7];
            #pragma unroll
            for (int nt = 0; nt < 7; ++nt) {
                const int c = nt * 16 + l15;
                bv[nt] = (c < 100) ? b1[c] : 0.f;
            }
            #pragma unroll
            for (int nt = 0; nt < 7; ++nt)
                #pragma unroll
                for (int r = 0; r < 4; ++r) {
                    const float v = fmaxf(acc[nt][r] + bv[nt], 0.f);
                    *(unsigned short*)(&L[sb_epi + r * SLAB_STRIDE + nt * 32]) =
                        f2bf(v);
                }
        }
        // zero cols 112..127 (100..111 zero via zero-padded frags)
        if (lane < 32)
            *(uint4*)(&L[sb + (lane >> 1) * SLAB_STRIDE + 224 + (lane & 1) * 16]) =
                make_uint4(0, 0, 0, 0);

        // ================= layer 2: h2 = relu(h1 @ W2 + b2) =============
        v4f acc2[7];
        #pragma unroll
        for (int nt = 0; nt < 7; ++nt) acc2[nt] = (v4f){0.f, 0.f, 0.f, 0.f};
        #pragma unroll
        for (int kc = 0; kc < 4; ++kc) {
            uint4 bu[7];
            #pragma unroll
            for (int nt = 0; nt < 7; ++nt) bu[nt] = FRAG_W2(nt * 4 + kc);
            uint4 t0 = *(const uint4*)(&L[sb_rd + kc * 64]);
            const v8s af = *(v8s*)&t0;
            #pragma unroll
            for (int nt = 0; nt < 7; ++nt)
                acc2[nt] = mfma16(af, *(const v8s*)&bu[nt], acc2[nt]);
        }
        // h2 overwrites h1 in-place (in-wave DS ordering); pads keep zeros
        {
            float bv[7];
            #pragma unroll
            for (int nt = 0; nt < 7; ++nt) {
                const int c = nt * 16 + l15;
                bv[nt] = (c < 100) ? b2[c] : 0.f;
            }
            #pragma unroll
            for (int nt = 0; nt < 7; ++nt)
                #pragma unroll
                for (int r = 0; r < 4; ++r) {
                    const float v = fmaxf(acc2[nt][r] + bv[nt], 0.f);
                    *(unsigned short*)(&L[sb_epi + r * SLAB_STRIDE + nt * 32]) =
                        f2bf(v);
                }
        }

        // ================= layer 3: DP = h2 @ W3 + b3 ===================
        v4f acc3[4];
        #pragma unroll
        for (int nt = 0; nt < 4; ++nt) acc3[nt] = (v4f){0.f, 0.f, 0.f, 0.f};
        #pragma unroll
        for (int kc = 0; kc < 4; ++kc) {
            uint4 bu[4];
            #pragma unroll
            for (int nt = 0; nt < 4; ++nt) bu[nt] = FRAG_W3(nt * 4 + kc);
            uint4 t0 = *(const uint4*)(&L[sb_rd + kc * 64]);
            const v8s af = *(v8s*)&t0;
            #pragma unroll
            for (int nt = 0; nt < 4; ++nt)
                acc3[nt] = mfma16(af, *(const v8s*)&bu[nt], acc3[nt]);
        }
        // DP (f32 [16][64]) overwrites slab (h2 reads precede in program order)
        {
            float bv[4];
            #pragma unroll
            for (int nt = 0; nt < 4; ++nt) bv[nt] = b3[nt * 16 + l15];
            #pragma unroll
            for (int nt = 0; nt < 4; ++nt)
                #pragma unroll
                for (int r = 0; r < 4; ++r)
                    *(float*)(&L[sb_dpw + r * SLAB_STRIDE + nt * 64]) =
                        acc3[nt][r] + bv[nt];
        }

        // ====== Student-t GAS recurrence: lane<16 owns one row ======
        if (lane < 16) {
            float mu = mu_init;
            float s2 = s2_init;
#define GAS_STEP(Y, O)                                                  \
            {   const float e    = (Y) - mu;                            \
                const float nus2 = anu * s2;                            \
                const float den  = fmaf(e, e, nus2);                    \
                const float r0   = __builtin_amdgcn_rcpf(den);          \
                const float p    = e * nus2 * r0;                       \
                mu = fmaf(cmu, p, fmaf(bMu, mu, oMu));                  \
                s2 = fmaf(cs, e * p, fmaf(bs2, s2, oSg));               \
                (O) = fmaf((Y), __builtin_amdgcn_sqrtf(s2), mu); }
            #pragma unroll
            for (int q = 0; q < 16; ++q) {
                float4 d = *(float4*)(&L[sb_gas + q * 16]);
                float o0, o1, o2, o3;
                GAS_STEP(d.x, o0); GAS_STEP(d.y, o1);
                GAS_STEP(d.z, o2); GAS_STEP(d.w, o3);
                *(float4*)(&L[sb_gas + q * 16]) = make_float4(o0, o1, o2, o3);
            }
#undef GAS_STEP
        }

        // ============ wave-wide coalesced float4 store (no barrier) =======
        #pragma unroll
        for (int i = 0; i < 4; ++i) {
            float4 v = *(float4*)(&L[sb_st + i * (4 * SLAB_STRIDE)]);
            ((float4*)out)[gw * 16 + i * 64 + lane] = v;
        }
    }
#undef FRAG_W1
#undef FRAG_W2
#undef FRAG_W3
#undef XLOADT
}

extern "C" void kernel_launch(void* const* d_in, const int* in_sizes, int n_in,
                              void* d_out, int out_size, void* d_ws, size_t ws_size,
                              hipStream_t stream) {
    const float* x          = (const float*)d_in[0];
    const float* last_mu    = (const float*)d_in[1];
    const float* last_sigma = (const float*)d_in[2];
    const float* amu        = (const float*)d_in[3];
    const float* asig       = (const float*)d_in[4];
    const float* bmu        = (const float*)d_in[5];
    const float* bsig       = (const float*)d_in[6];
    const float* omu        = (const float*)d_in[7];
    const float* osig       = (const float*)d_in[8];
    const float* nu         = (const float*)d_in[9];
    const float* ns         = (const float*)d_in[10];
    const float* W1         = (const float*)d_in[11];
    const float* b1         = (const float*)d_in[12];
    const float* W2         = (const float*)d_in[13];
    const float* b2         = (const float*)d_in[14];
    const float* W3         = (const float*)d_in[15];
    const float* b3         = (const float*)d_in[16];
    float* out = (float*)d_out;

    uint4* wf = (uint4*)d_ws;   // 95,232 B fragment table (93 frags)
    prep_weights<<<93, 64, 0, stream>>>(W1, W2, W3, wf);

    hipFuncSetAttribute((const void*)ar_gas_v23,
                        hipFuncAttributeMaxDynamicSharedMemorySize, LDS_TOTAL);

    const int B = in_sizes[1];                 // 262144
    dim3 grid(B / BMROWS), block(THREADS);     // 256 blocks = 1 per CU
    ar_gas_v23<<<grid, block, LDS_TOTAL, stream>>>(
        x, last_mu, last_sigma,
        amu, asig, bmu, bsig, omu, osig, nu, ns,
        b1, b2, b3, wf, out);
}